// Round 1
// baseline (386.212 us; speedup 1.0000x reference)
//
#include <hip/hip_runtime.h>

#define D 128
#define S 16

// Fused KGCN: attention + neighbor aggregation + 2x relu((msg+rep)@W+b) +
// final dot/sigmoid in ONE kernel. 8 elements/block (32 lanes each, 4 dims
// per lane), grid 1024 -> 4 blocks/CU, 16 waves/CU.
//
// vs the previous 2-kernel version this removes:
//  - the 4 MiB msg round-trip through d_ws (8 MB HBM traffic),
//  - the k2 launch + k1-tail serialization,
//  - duplicate usr[u]/ent[v] gathers (u4/rep0 stay in registers).
//
// Phase-1 load schedule: rel chunk0 -> ent chunk0 ISSUED -> scores chunk0
// (waits only rel0; ent0 stays in flight) -> rel chunk1 -> scores chunk1 ->
// softmax -> ent chunk1 -> msg. ent chunk0's ~900-cyc HBM latency is hidden
// under sc0+rel1+sc1+softmax. Peak live regs ~105 (r4+n4a+sc) -> 4 waves/SIMD.
//
// Phase-2 matmul: x row broadcast from LDS (same-address read = free),
// W row read coalesced 512B/group (W = 64 KB, L1/L2-resident, shared by all
// groups in lockstep). Barriers separate LDS read phases from the x1
// overwrite (cross-lane WAR through LDS is NOT ordered by same-thread deps).
__global__ __launch_bounds__(256) void kgcn_fused(
    const int* __restrict__ u, const int* __restrict__ v,
    const int* __restrict__ adj_ent, const int* __restrict__ adj_rel,
    const float* __restrict__ usr, const float* __restrict__ ent,
    const float* __restrict__ rel, const float* __restrict__ W,
    const float* __restrict__ bias, float* __restrict__ out)
{
    __shared__ float sX[8 * D];     // 4 KB: per-element x row

    const int tid  = threadIdx.x;
    const int grp  = tid >> 5;      // element slot 0..7
    const int lane = tid & 31;      // 4 dims per lane
    const int b    = blockIdx.x * 8 + grp;

    const int uu = u[b];
    const int vv = v[b];

    const float4 u4   = *(const float4*)(usr + (size_t)uu * D + lane * 4);
    const float4 rep0 = *(const float4*)(ent + (size_t)vv * D + lane * 4);

    // lanes 0..15 hold the adjacency row; shuffled out per s
    const int ae = adj_ent[(size_t)vv * S + (lane & 15)];
    const int ar = adj_rel[(size_t)vv * S + (lane & 15)];

    float sc[S];
    float4 r4[8], n4a[8], n4b[8];

    // rel chunk 0 (L1-resident: rel table = 32 KB total)
    #pragma unroll
    for (int s = 0; s < 8; ++s) {
        const int nr = __shfl(ar, s, 32);
        r4[s] = *(const float4*)(rel + (size_t)nr * D + lane * 4);
    }
    // ent chunk 0: ISSUE now, consume after softmax (latency overlap)
    #pragma unroll
    for (int s = 0; s < 8; ++s) {
        const int ne = __shfl(ae, s, 32);
        n4a[s] = *(const float4*)(ent + (size_t)ne * D + lane * 4);
    }
    // scores chunk 0 (only waits on rel chunk 0 — oldest 8 outstanding)
    #pragma unroll
    for (int s = 0; s < 8; ++s) {
        float p = u4.x * r4[s].x + u4.y * r4[s].y +
                  u4.z * r4[s].z + u4.w * r4[s].w;
        #pragma unroll
        for (int off = 16; off >= 1; off >>= 1) p += __shfl_xor(p, off, 32);
        sc[s] = p;
    }
    // rel chunk 1 (reuses r4 regs)
    #pragma unroll
    for (int s = 0; s < 8; ++s) {
        const int nr = __shfl(ar, 8 + s, 32);
        r4[s] = *(const float4*)(rel + (size_t)nr * D + lane * 4);
    }
    #pragma unroll
    for (int s = 0; s < 8; ++s) {
        float p = u4.x * r4[s].x + u4.y * r4[s].y +
                  u4.z * r4[s].z + u4.w * r4[s].w;
        #pragma unroll
        for (int off = 16; off >= 1; off >>= 1) p += __shfl_xor(p, off, 32);
        sc[8 + s] = p;
    }

    // softmax over S=16 (same op order as the passing kernel -> absmax 0)
    float mx = sc[0];
    #pragma unroll
    for (int s = 1; s < S; ++s) mx = fmaxf(mx, sc[s]);
    float sum = 0.f;
    #pragma unroll
    for (int s = 0; s < S; ++s) { sc[s] = __expf(sc[s] - mx); sum += sc[s]; }
    const float inv = 1.f / sum;

    // ent chunk 1: issue before consuming chunk 0
    #pragma unroll
    for (int s = 0; s < 8; ++s) {
        const int ne = __shfl(ae, 8 + s, 32);
        n4b[s] = *(const float4*)(ent + (size_t)ne * D + lane * 4);
    }

    float m0 = 0.f, m1 = 0.f, m2 = 0.f, m3 = 0.f;
    #pragma unroll
    for (int s = 0; s < 8; ++s) {
        const float a = sc[s] * inv;
        m0 += a * n4a[s].x; m1 += a * n4a[s].y;
        m2 += a * n4a[s].z; m3 += a * n4a[s].w;
    }
    #pragma unroll
    for (int s = 0; s < 8; ++s) {
        const float a = sc[8 + s] * inv;
        m0 += a * n4b[s].x; m1 += a * n4b[s].y;
        m2 += a * n4b[s].z; m3 += a * n4b[s].w;
    }

    // ---- phase 2: two relu((msg+rep)@W+b) layers, all within the group ----
    const int j0 = lane * 4;
    const float4 b4 = *(const float4*)(bias + j0);
    const float* xrow = &sX[grp * D];

    // x0 = msg + rep0
    *(float4*)&sX[grp * D + j0] =
        make_float4(m0 + rep0.x, m1 + rep0.y, m2 + rep0.z, m3 + rep0.w);
    __syncthreads();

    float4 y;
    {   // layer 1
        float a0 = 0.f, a1 = 0.f, a2 = 0.f, a3 = 0.f;
        #pragma unroll 4
        for (int d = 0; d < D; ++d) {
            const float4 w4 = *(const float4*)(W + d * D + j0);
            const float xm = xrow[d];           // LDS broadcast (free)
            a0 += xm * w4.x; a1 += xm * w4.y;
            a2 += xm * w4.z; a3 += xm * w4.w;
        }
        y.x = fmaxf(a0 + b4.x, 0.f);
        y.y = fmaxf(a1 + b4.y, 0.f);
        y.z = fmaxf(a2 + b4.z, 0.f);
        y.w = fmaxf(a3 + b4.w, 0.f);
    }
    __syncthreads();   // all x0 reads done before x1 overwrite (cross-lane WAR)

    // x1 = msg + rep1
    *(float4*)&sX[grp * D + j0] =
        make_float4(m0 + y.x, m1 + y.y, m2 + y.z, m3 + y.w);
    __syncthreads();

    {   // layer 2
        float a0 = 0.f, a1 = 0.f, a2 = 0.f, a3 = 0.f;
        #pragma unroll 4
        for (int d = 0; d < D; ++d) {
            const float4 w4 = *(const float4*)(W + d * D + j0);
            const float xm = xrow[d];
            a0 += xm * w4.x; a1 += xm * w4.y;
            a2 += xm * w4.z; a3 += xm * w4.w;
        }
        y.x = fmaxf(a0 + b4.x, 0.f);
        y.y = fmaxf(a1 + b4.y, 0.f);
        y.z = fmaxf(a2 + b4.z, 0.f);
        y.w = fmaxf(a3 + b4.w, 0.f);
    }

    // out = sigmoid(u_emb . rep2) — u4 already in registers
    float pr = u4.x * y.x + u4.y * y.y + u4.z * y.z + u4.w * y.w;
    #pragma unroll
    for (int off = 16; off >= 1; off >>= 1) pr += __shfl_xor(pr, off, 32);
    if (lane == 0) out[b] = 1.f / (1.f + __expf(-pr));
}

extern "C" void kernel_launch(void* const* d_in, const int* in_sizes, int n_in,
                              void* d_out, int out_size, void* d_ws, size_t ws_size,
                              hipStream_t stream)
{
    const int* u       = (const int*)d_in[0];
    const int* v       = (const int*)d_in[1];
    const int* adj_ent = (const int*)d_in[2];
    const int* adj_rel = (const int*)d_in[3];
    const float* usr   = (const float*)d_in[4];
    const float* ent   = (const float*)d_in[5];
    const float* rel   = (const float*)d_in[6];
    const float* W     = (const float*)d_in[7];
    const float* bias  = (const float*)d_in[8];
    float* out = (float*)d_out;

    hipLaunchKernelGGL(kgcn_fused, dim3(8192 / 8), dim3(256), 0, stream,
                       u, v, adj_ent, adj_rel, usr, ent, rel, W, bias, out);
}

// Round 3
// 376.175 us; speedup vs baseline: 1.0267x; 1.0267x over previous
//
#include <hip/hip_runtime.h>

#define D 128
#define S 16

// Fused KGCN v3: 16 elements/block, 256 threads, grid 512 -> 2 blocks/CU.
// De-risked after the v2 (512-thread, launch_bounds(512,2)) container
// failure: every structure here is a proven piece from the round-0/1
// passing kernels; only the phase-2 W-reuse tiling is new.
//
// Phase 1 (gather/attention): 8 groups of 32 lanes, 2 elements each
// (#pragma unroll 1 -> ~110 live VGPRs). Per element: rel chunk0 ->
// ent chunk0 ISSUED early -> scores chunk0 -> rel chunk1 -> scores chunk1
// -> softmax -> ent chunk1 -> msg. msg and x0=msg+rep0 go to LDS; u4 stays
// in registers for phase 3.
//
// Phase 2 (two relu((msg+rep)@W+b) layers): column-split register tile.
// Group g = (gc, gr): gc = g&1 picks column half (j0 = gc*64 + ln*2),
// gr = g>>1 picks row quad (m0 = gr*4). Each lane loads ONE float2 of W
// per d and reuses it across 4 rows -> W request traffic 1 GB (round 1,
// M=1) -> 256 MB (M=4). x rows read as broadcast ds_read_b128.
// NOTE: rows are shared by the gc=0 and gc=1 groups, so the x1 overwrite
// is a cross-wave WAR through LDS -> y is kept in registers and a
// __syncthreads() separates the x0 reads from the x1 writes.
//
// Phase 3 (dot/sigmoid): identical to round-1 (4-consecutive-cols per
// lane + 5-step xor tree) -> bit-exact.
//
// FP op order identical to the round-0/1 passing kernels everywhere ->
// absmax stays 0.
__global__ __launch_bounds__(256) void kgcn_fused(
    const int* __restrict__ u, const int* __restrict__ v,
    const int* __restrict__ adj_ent, const int* __restrict__ adj_rel,
    const float* __restrict__ usr, const float* __restrict__ ent,
    const float* __restrict__ rel, const float* __restrict__ W,
    const float* __restrict__ bias, float* __restrict__ out)
{
    __shared__ float sX[16 * D];     // 8 KB: x0 rows, then x1, then rep2
    __shared__ float sMsg[16 * D];   // 8 KB: msg rows

    const int tid = threadIdx.x;
    const int g   = tid >> 5;        // 8 groups
    const int ln  = tid & 31;
    const int b0  = blockIdx.x * 16;

    float4 u4k[2];                   // u rows kept in regs for phase 3

    // ---------------- phase 1: attention + neighbor aggregation ----------
    #pragma unroll 1
    for (int i = 0; i < 2; ++i) {
        const int e  = g * 2 + i;
        const int b  = b0 + e;
        const int uu = u[b];
        const int vv = v[b];

        const float4 u4   = *(const float4*)(usr + (size_t)uu * D + ln * 4);
        const float4 rep0 = *(const float4*)(ent + (size_t)vv * D + ln * 4);

        // lanes 0..15 hold the adjacency row; shuffled out per s
        const int ae = adj_ent[(size_t)vv * S + (ln & 15)];
        const int ar = adj_rel[(size_t)vv * S + (ln & 15)];

        float sc[S];
        float4 r4[8], n4a[8], n4b[8];

        // rel chunk 0 (rel table = 32 KB, L1-resident)
        #pragma unroll
        for (int s = 0; s < 8; ++s) {
            const int nr = __shfl(ar, s, 32);
            r4[s] = *(const float4*)(rel + (size_t)nr * D + ln * 4);
        }
        // ent chunk 0: ISSUE now, consume after softmax (latency overlap)
        #pragma unroll
        for (int s = 0; s < 8; ++s) {
            const int ne = __shfl(ae, s, 32);
            n4a[s] = *(const float4*)(ent + (size_t)ne * D + ln * 4);
        }
        // scores chunk 0 (waits only on rel chunk 0)
        #pragma unroll
        for (int s = 0; s < 8; ++s) {
            float p = u4.x * r4[s].x + u4.y * r4[s].y +
                      u4.z * r4[s].z + u4.w * r4[s].w;
            #pragma unroll
            for (int off = 16; off >= 1; off >>= 1) p += __shfl_xor(p, off, 32);
            sc[s] = p;
        }
        // rel chunk 1 (reuses r4 regs)
        #pragma unroll
        for (int s = 0; s < 8; ++s) {
            const int nr = __shfl(ar, 8 + s, 32);
            r4[s] = *(const float4*)(rel + (size_t)nr * D + ln * 4);
        }
        #pragma unroll
        for (int s = 0; s < 8; ++s) {
            float p = u4.x * r4[s].x + u4.y * r4[s].y +
                      u4.z * r4[s].z + u4.w * r4[s].w;
            #pragma unroll
            for (int off = 16; off >= 1; off >>= 1) p += __shfl_xor(p, off, 32);
            sc[8 + s] = p;
        }

        // softmax over S=16 (same op order as passing kernels)
        float mx = sc[0];
        #pragma unroll
        for (int s = 1; s < S; ++s) mx = fmaxf(mx, sc[s]);
        float sum = 0.f;
        #pragma unroll
        for (int s = 0; s < S; ++s) { sc[s] = __expf(sc[s] - mx); sum += sc[s]; }
        const float inv = 1.f / sum;

        // ent chunk 1: issue before consuming chunk 0
        #pragma unroll
        for (int s = 0; s < 8; ++s) {
            const int ne = __shfl(ae, 8 + s, 32);
            n4b[s] = *(const float4*)(ent + (size_t)ne * D + ln * 4);
        }

        float m0 = 0.f, m1 = 0.f, m2 = 0.f, m3 = 0.f;
        #pragma unroll
        for (int s = 0; s < 8; ++s) {
            const float a = sc[s] * inv;
            m0 += a * n4a[s].x; m1 += a * n4a[s].y;
            m2 += a * n4a[s].z; m3 += a * n4a[s].w;
        }
        #pragma unroll
        for (int s = 0; s < 8; ++s) {
            const float a = sc[8 + s] * inv;
            m0 += a * n4b[s].x; m1 += a * n4b[s].y;
            m2 += a * n4b[s].z; m3 += a * n4b[s].w;
        }

        *(float4*)&sMsg[e * D + ln * 4] = make_float4(m0, m1, m2, m3);
        *(float4*)&sX[e * D + ln * 4] =
            make_float4(m0 + rep0.x, m1 + rep0.y, m2 + rep0.z, m3 + rep0.w);
        u4k[i] = u4;
    }
    __syncthreads();

    // ---------------- phase 2: two layers, 4-row x 2-col register tile ---
    const int gc  = g & 1;           // column half
    const int gr  = g >> 1;          // row quad
    const int m0r = gr * 4;
    const int j0  = gc * 64 + ln * 2;
    const float2 b2 = *(const float2*)(bias + j0);

    float y[4][2];

    {   // ---- layer 1: y = relu(x0 @ W + b) ----
        float acc[4][2];
        #pragma unroll
        for (int k = 0; k < 4; ++k) { acc[k][0] = 0.f; acc[k][1] = 0.f; }

        #pragma unroll 4
        for (int d0 = 0; d0 < D; d0 += 4) {
            float4 xv[4];
            #pragma unroll
            for (int k = 0; k < 4; ++k)
                xv[k] = *(const float4*)&sX[(m0r + k) * D + d0];
            #pragma unroll
            for (int dd = 0; dd < 4; ++dd) {
                const float2 w2 = *(const float2*)(W + (d0 + dd) * D + j0);
                #pragma unroll
                for (int k = 0; k < 4; ++k) {
                    const float xm = dd == 0 ? xv[k].x : dd == 1 ? xv[k].y
                                   : dd == 2 ? xv[k].z : xv[k].w;
                    acc[k][0] += xm * w2.x; acc[k][1] += xm * w2.y;
                }
            }
        }
        #pragma unroll
        for (int k = 0; k < 4; ++k) {
            y[k][0] = fmaxf(acc[k][0] + b2.x, 0.f);
            y[k][1] = fmaxf(acc[k][1] + b2.y, 0.f);
        }
    }
    __syncthreads();   // all x0 reads done before x1 overwrite (cross-wave WAR)

    // x1 = msg + y
    #pragma unroll
    for (int k = 0; k < 4; ++k) {
        const float2 mg2 = *(const float2*)&sMsg[(m0r + k) * D + j0];
        *(float2*)&sX[(m0r + k) * D + j0] =
            make_float2(mg2.x + y[k][0], mg2.y + y[k][1]);
    }
    __syncthreads();

    {   // ---- layer 2: rep2 = relu(x1 @ W + b) ----
        float acc[4][2];
        #pragma unroll
        for (int k = 0; k < 4; ++k) { acc[k][0] = 0.f; acc[k][1] = 0.f; }

        #pragma unroll 4
        for (int d0 = 0; d0 < D; d0 += 4) {
            float4 xv[4];
            #pragma unroll
            for (int k = 0; k < 4; ++k)
                xv[k] = *(const float4*)&sX[(m0r + k) * D + d0];
            #pragma unroll
            for (int dd = 0; dd < 4; ++dd) {
                const float2 w2 = *(const float2*)(W + (d0 + dd) * D + j0);
                #pragma unroll
                for (int k = 0; k < 4; ++k) {
                    const float xm = dd == 0 ? xv[k].x : dd == 1 ? xv[k].y
                                   : dd == 2 ? xv[k].z : xv[k].w;
                    acc[k][0] += xm * w2.x; acc[k][1] += xm * w2.y;
                }
            }
        }
        #pragma unroll
        for (int k = 0; k < 4; ++k) {
            y[k][0] = fmaxf(acc[k][0] + b2.x, 0.f);
            y[k][1] = fmaxf(acc[k][1] + b2.y, 0.f);
        }
    }
    __syncthreads();   // all x1 reads done before rep2 overwrite

    #pragma unroll
    for (int k = 0; k < 4; ++k)
        *(float2*)&sX[(m0r + k) * D + j0] = make_float2(y[k][0], y[k][1]);
    __syncthreads();

    // ---------------- phase 3: out = sigmoid(u . rep2) --------------------
    #pragma unroll
    for (int i = 0; i < 2; ++i) {
        const int e = g * 2 + i;
        const float4 rf = *(const float4*)&sX[e * D + ln * 4];
        const float4 uf = u4k[i];
        float pr = uf.x * rf.x + uf.y * rf.y + uf.z * rf.z + uf.w * rf.w;
        #pragma unroll
        for (int off = 16; off >= 1; off >>= 1) pr += __shfl_xor(pr, off, 32);
        if (ln == 0) out[b0 + e] = 1.f / (1.f + __expf(-pr));
    }
}

extern "C" void kernel_launch(void* const* d_in, const int* in_sizes, int n_in,
                              void* d_out, int out_size, void* d_ws, size_t ws_size,
                              hipStream_t stream)
{
    const int* u       = (const int*)d_in[0];
    const int* v       = (const int*)d_in[1];
    const int* adj_ent = (const int*)d_in[2];
    const int* adj_rel = (const int*)d_in[3];
    const float* usr   = (const float*)d_in[4];
    const float* ent   = (const float*)d_in[5];
    const float* rel   = (const float*)d_in[6];
    const float* W     = (const float*)d_in[7];
    const float* bias  = (const float*)d_in[8];
    float* out = (float*)d_out;

    hipLaunchKernelGGL(kgcn_fused, dim3(8192 / 16), dim3(256), 0, stream,
                       u, v, adj_ent, adj_rel, usr, ent, rel, W, bias, out);
}